// Round 15
// baseline (171.682 us; speedup 1.0000x reference)
//
#include <hip/hip_runtime.h>
#include <hip/hip_bf16.h>
#include <float.h>

#define Bc 32
#define Nc 512
#define Dc 128
#define Hc 8
#define DKc 16
#define Ec 128
#define LOG2E 1.44269504088896340736f
#define SCLAMP 80.0f

typedef __attribute__((ext_vector_type(4))) short s16x4;
typedef __attribute__((ext_vector_type(8))) short s16x8;
typedef __attribute__((ext_vector_type(4))) float f32x4;

union BFU { __hip_bfloat16 b; short s; };
static __device__ inline short f2bf(float f) { BFU u; u.b = __float2bfloat16(f); return u.s; }
static __device__ inline s16x4 pack4(float a, float b, float c, float d) {
  s16x4 r; r[0] = f2bf(a); r[1] = f2bf(b); r[2] = f2bf(c); r[3] = f2bf(d); return r;
}

#if __has_builtin(__builtin_amdgcn_exp2f)
#define EXP2F(x) __builtin_amdgcn_exp2f(x)
#else
#define EXP2F(x) exp2f(x)
#endif

// D = A*B + C for 16x16x16 bf16. A[m=l&15][k=(l>>4)*4+i]; B[k=(l>>4)*4+i][n=l&15];
// C/D: col(n)=l&15, row(m)=(l>>4)*4+reg.
static __device__ inline f32x4 mfma16(s16x4 a, s16x4 b, f32x4 c) {
#if __has_builtin(__builtin_amdgcn_mfma_f32_16x16x16bf16_1k)
  return __builtin_amdgcn_mfma_f32_16x16x16bf16_1k(a, b, c, 0, 0, 0);
#else
  int lane = threadIdx.x & 63;
  int g = lane >> 4, base = lane & 15;
  int src0 = (base + 32 * g) & 63;
  int src1 = (base + 32 * g + 16) & 63;
  int ax = ((int*)&a)[0], ay = ((int*)&a)[1];
  int bx = ((int*)&b)[0], by = ((int*)&b)[1];
  int A0 = __shfl(ax, src0), A1 = __shfl(ay, src0);
  int A2 = __shfl(ax, src1), A3 = __shfl(ay, src1);
  int B0 = __shfl(bx, src0), B1 = __shfl(by, src0);
  int B2 = __shfl(bx, src1), B3 = __shfl(by, src1);
  if (g >= 2) { A0 = A1 = A2 = A3 = 0; B0 = B1 = B2 = B3 = 0; }
  s16x8 A8, B8;
  ((int*)&A8)[0] = A0; ((int*)&A8)[1] = A1; ((int*)&A8)[2] = A2; ((int*)&A8)[3] = A3;
  ((int*)&B8)[0] = B0; ((int*)&B8)[1] = B1; ((int*)&B8)[2] = B2; ((int*)&B8)[3] = B3;
  return __builtin_amdgcn_mfma_f32_16x16x32_bf16(A8, B8, c, 0, 0, 0);
#endif
}

// ---- prep: weight conv (0..255) + mask detector (256) + 1024-cell table (257..260) ----
// tabI[h*1024 + c] = (bf16(f(mid)*L)<<16) | bf16(a*L); cells over [-8,8), width 1/64.
__global__ __launch_bounds__(256) void prep_all(
    const float* __restrict__ Wq, const float* __restrict__ Wk, const float* __restrict__ Wv,
    const float* __restrict__ Wo,
    const unsigned char* __restrict__ m, int* __restrict__ flag,
    const float* __restrict__ mW1, const float* __restrict__ mb1,
    const float* __restrict__ mW2, const float* __restrict__ mb2,
    const float* __restrict__ mW3, const float* __restrict__ mb3,
    short* __restrict__ Wt, short* __restrict__ Wob, int* __restrict__ tabI)
{
  int blk = blockIdx.x;
  int t = threadIdx.x;

  if (blk == 256) {   // mask-format detector (single-writer)
    __shared__ int red[4];
    int any = 0;
    for (int u = t; u < 16384; u += 256)
      if ((u & 3) != 0 && m[u] != 0) any = 1;
    unsigned long long bal = __ballot(any != 0);
    if ((t & 63) == 0) red[t >> 6] = (bal != 0ULL) ? 1 : 0;
    __syncthreads();
    if (t == 0) *flag = red[0] | red[1] | red[2] | red[3];
    return;
  }

  if (blk >= 257) {   // cell table: exact MLP tangent-segment at cell midpoint
    __shared__ float wl[440];
    for (int u = t; u < 440; u += 256) {
      float v;
      if (u < 16) v = mW1[u];
      else if (u < 32)  v = mb1[u - 16];
      else if (u < 288) v = mW2[u - 32];
      else if (u < 304) v = mb2[u - 288];
      else if (u < 432) v = mW3[u - 304];
      else v = mb3[u - 432];
      wl[u] = v;
    }
    __syncthreads();
    int c = (blk - 257) * 256 + t;                       // 0..1023
    float mm = fmaf((float)c, 0.015625f, -7.9921875f);   // -8 + 1/128 + c/64

    float pre[16];
    #pragma unroll
    for (int u = 0; u < 16; ++u) pre[u] = fmaf(mm, wl[u], wl[16 + u]);
    float a2[16], v2[16];
    #pragma unroll
    for (int v = 0; v < 16; ++v) { a2[v] = 0.f; v2[v] = wl[288 + v]; }
    #pragma unroll
    for (int u = 0; u < 16; ++u) {
      bool act = pre[u] > 0.f;
      float w1 = act ? wl[u] : 0.f;
      float pp = act ? pre[u] : 0.f;
      #pragma unroll
      for (int v = 0; v < 16; ++v) {
        float w2 = wl[32 + u * 16 + v];
        a2[v] = fmaf(w1, w2, a2[v]);
        v2[v] = fmaf(pp, w2, v2[v]);
      }
    }
    float ah[8], fh[8];
    #pragma unroll
    for (int h = 0; h < 8; ++h) { ah[h] = 0.f; fh[h] = wl[432 + h]; }
    #pragma unroll
    for (int v = 0; v < 16; ++v) {
      bool act = v2[v] > 0.f;
      float av = act ? a2[v] : 0.f;
      float vv = act ? v2[v] : 0.f;
      #pragma unroll
      for (int h = 0; h < 8; ++h) {
        float w3 = wl[304 + v * 8 + h];
        ah[h] = fmaf(av, w3, ah[h]);
        fh[h] = fmaf(vv, w3, fh[h]);
      }
    }
    #pragma unroll
    for (int h = 0; h < 8; ++h) {
      int ab = (int)(unsigned short)(f2bf(ah[h] * LOG2E));
      int fb = ((int)f2bf(fh[h] * LOG2E)) << 16;
      tabI[h * 1024 + c] = fb | ab;                      // head-major for b32 LDS gather
    }
    return;
  }

  int o = blk * 256 + t;
  if (o < 49152) {
    int mat = o >> 14, r = o & 16383;
    int hk = r >> 7, d = r & 127;
    const float* src = (mat == 0) ? Wq : ((mat == 1) ? Wk : Wv);
    Wt[o] = f2bf(src[(hk >> 4) * 2048 + d * 16 + (hk & 15)]);
  } else {
    int o2 = o - 49152;
    int et = o2 >> 11, s = (o2 >> 8) & 7, lane = (o2 >> 2) & 63, i = o2 & 3;
    Wob[o2] = f2bf(Wo[(s * 16 + (lane >> 4) * 4 + i) * 128 + et * 16 + (lane & 15)]);
  }
}

// ---- kernel A: QKV projection via MFMA (unchanged, verified) ----
__global__ __launch_bounds__(256, 4) void qkv4(
    const float* __restrict__ q, const short* __restrict__ Wt,
    short* __restrict__ Qb, short* __restrict__ Kb, short* __restrict__ Vt)
{
  __shared__ short qs[16][136];
  int blk = blockIdx.x;
  int b = blk >> 5;
  int rt = (blk & 31) << 4;
  int t = threadIdx.x;
  int wid = t >> 6, lane = t & 63;
  int lq = lane & 15, lg = lane >> 4;

  #pragma unroll
  for (int it = 0; it < 2; ++it) {
    int u = t + it * 256;
    int row = u >> 5, c4 = (u & 31) << 2;
    float4 v = *(const float4*)&q[((((b << 9) + rt + row) << 7)) + c4];
    *(s16x4*)&qs[row][c4] = pack4(v.x, v.y, v.z, v.w);
  }
  __syncthreads();

  s16x4 af[8];
  #pragma unroll
  for (int ks = 0; ks < 8; ++ks)
    af[ks] = *(const s16x4*)&qs[lq][ks * 16 + lg * 4];

  #pragma unroll 1
  for (int pj = 0; pj < 3; ++pj) {
    const short* Wm = Wt + pj * 16384;
    #pragma unroll
    for (int c2 = 0; c2 < 2; ++c2) {
      int ct = wid * 2 + c2;
      f32x4 acc = (f32x4)0.f;
      #pragma unroll
      for (int ks = 0; ks < 8; ++ks) {
        s16x4 bf = *(const s16x4*)&Wm[(ct * 16 + lq) * 128 + ks * 16 + lg * 4];
        acc = mfma16(af[ks], bf, acc);
      }
      if (pj == 0) {
        s16x4 pk = pack4(acc[0] * (0.25f * LOG2E), acc[1] * (0.25f * LOG2E),
                         acc[2] * (0.25f * LOG2E), acc[3] * (0.25f * LOG2E));
        #pragma unroll
        for (int r = 0; r < 4; ++r)
          Qb[(ct << 18) + (b << 13) + ((rt + lg * 4 + r) << 4) + lq] = pk[r];
      } else if (pj == 1) {
        s16x4 pk = pack4(acc[0], acc[1], acc[2], acc[3]);
        #pragma unroll
        for (int r = 0; r < 4; ++r)
          Kb[(ct << 18) + (b << 13) + ((rt + lg * 4 + r) << 4) + lq] = pk[r];
      } else {
        s16x4 pk = pack4(acc[0], acc[1], acc[2], acc[3]);
        *(s16x4*)&Vt[(ct << 18) + (((b << 4) + lq) << 9) + rt + lg * 4] = pk;
      }
    }
  }
}

// ---- kernel B: 8-wave attn, straight-line 4-way sub-chunk ILP ----
// 512 threads; wave w owns chunks {w, w+8, w+16, w+24}, all in one unrolled body.
// Gathers: 16 precomputed byte-addrs, per-head read = same vaddr + imm offset h*4096.
// LDS 36864B: tabL int[8][1024] @0; epilogue overlay obfL [8w][8h][64] s16x4 @0
// + psL f32[8][8][16] @32768. launch_bounds(512,4): VGPR cap 128 = 2-block tier
// (r13's natural tier; cap prevents transient bloat, graceful ILP trade if tight).
__global__ __launch_bounds__(512, 4) void attn15(
    const float* __restrict__ edge, const unsigned char* __restrict__ maskB,
    const int* __restrict__ flag,
    const short* __restrict__ Qb, const short* __restrict__ Kb, const short* __restrict__ Vt,
    const short* __restrict__ Wob,
    const int* __restrict__ tabI,
    float* __restrict__ out)
{
  __shared__ __align__(16) char smem[36864];

  int t = threadIdx.x;
  int wid = t >> 6, lane = t & 63;
  int lq = lane & 15, lg = lane >> 4;
  int b = blockIdx.x >> 5;
  int qt = (blockIdx.x & 31) << 4;
  int mflag = *flag;

  s16x4* obfL = (s16x4*)smem;                 // [8w][8h][64] overlay
  float* psL = (float*)(smem + 32768);        // [8][8][16]

  const short* Kl = Kb + (b << 13) + (lq << 4) + (lg << 2);
  const short* Vl = Vt + (((b << 4) + lq) << 9) + (lg << 2);
  const short* Ql = Qb + (b << 13) + ((qt + lq) << 4) + (lg << 2);
  unsigned mbase = (((b << 9) + qt + lq) << 9) + (lg << 2);

  // issue all 4 sub-chunks' edge + mask loads up front (overlap with staging)
  int jb0 = wid << 4, jb1 = (wid + 8) << 4, jb2 = (wid + 16) << 4, jb3 = (wid + 24) << 4;
  float4 ev0 = *(const float4*)&edge[mbase + jb0];
  float4 ev1 = *(const float4*)&edge[mbase + jb1];
  float4 ev2 = *(const float4*)&edge[mbase + jb2];
  float4 ev3 = *(const float4*)&edge[mbase + jb3];
  int4 mk0, mk1, mk2, mk3;
  if (mflag) {
    uchar4 u0 = *(const uchar4*)&maskB[mbase + jb0];
    uchar4 u1 = *(const uchar4*)&maskB[mbase + jb1];
    uchar4 u2 = *(const uchar4*)&maskB[mbase + jb2];
    uchar4 u3 = *(const uchar4*)&maskB[mbase + jb3];
    mk0.x = u0.x; mk0.y = u0.y; mk0.z = u0.z; mk0.w = u0.w;
    mk1.x = u1.x; mk1.y = u1.y; mk1.z = u1.z; mk1.w = u1.w;
    mk2.x = u2.x; mk2.y = u2.y; mk2.z = u2.z; mk2.w = u2.w;
    mk3.x = u3.x; mk3.y = u3.y; mk3.z = u3.z; mk3.w = u3.w;
  } else {
    const int* mi = (const int*)maskB;
    mk0 = *(const int4*)&mi[mbase + jb0];
    mk1 = *(const int4*)&mi[mbase + jb1];
    mk2 = *(const int4*)&mi[mbase + jb2];
    mk3 = *(const int4*)&mi[mbase + jb3];
  }

  // stage table (8192 ints = 2048 int4)
  for (int u = t; u < 2048; u += 512)
    ((int4*)smem)[u] = ((const int4*)tabI)[u];

  s16x4 qf[8];
  #pragma unroll
  for (int h = 0; h < 8; ++h) qf[h] = *(const s16x4*)(Ql + (h << 18));

  f32x4 oacc[8];
  float psum[8];
  #pragma unroll
  for (int h = 0; h < 8; ++h) { oacc[h] = (f32x4)0.f; psum[h] = 0.f; }

  // decode: 16 byte-addresses (ix<<2) + 16 em floats (static-indexed arrays)
  unsigned ab[16];
  float em[16];
  {
    const float* evp[4] = { (const float*)&ev0, (const float*)&ev1,
                            (const float*)&ev2, (const float*)&ev3 };
    #pragma unroll
    for (int s = 0; s < 4; ++s)
      #pragma unroll
      for (int r = 0; r < 4; ++r) {
        float e = evp[s][r];
        float fx = fminf(fmaxf(fmaf(e, 64.f, 512.f), 0.f), 1023.f);
        int ix = (int)fx;
        ab[s * 4 + r] = (unsigned)(ix << 2);
        em[s * 4 + r] = e - fmaf((float)ix, 0.015625f, -7.9921875f);
      }
  }

  __syncthreads();   // table staged

  // fully unrolled: 8 heads x 4 sub-chunks, all chains visible to scheduler
  #pragma unroll
  for (int h = 0; h < 8; ++h) {
    const char* tb = smem + (h << 12);
    int c[16];
    #pragma unroll
    for (int u = 0; u < 16; ++u) c[u] = *(const int*)(tb + ab[u]);
    s16x4 kf0 = *(const s16x4*)(Kl + (h << 18) + (jb0 << 4));
    s16x4 kf1 = *(const s16x4*)(Kl + (h << 18) + (jb1 << 4));
    s16x4 kf2 = *(const s16x4*)(Kl + (h << 18) + (jb2 << 4));
    s16x4 kf3 = *(const s16x4*)(Kl + (h << 18) + (jb3 << 4));
    s16x4 vf0 = *(const s16x4*)(Vl + (h << 18) + jb0);
    s16x4 vf1 = *(const s16x4*)(Vl + (h << 18) + jb1);
    s16x4 vf2 = *(const s16x4*)(Vl + (h << 18) + jb2);
    s16x4 vf3 = *(const s16x4*)(Vl + (h << 18) + jb3);

    f32x4 s0, s1, s2, s3;
    #pragma unroll
    for (int r = 0; r < 4; ++r) {
      s0[r] = fmaf(__int_as_float(c[r] << 16),      em[r],      __int_as_float(c[r] & 0xffff0000));
      s1[r] = fmaf(__int_as_float(c[4 + r] << 16),  em[4 + r],  __int_as_float(c[4 + r] & 0xffff0000));
      s2[r] = fmaf(__int_as_float(c[8 + r] << 16),  em[8 + r],  __int_as_float(c[8 + r] & 0xffff0000));
      s3[r] = fmaf(__int_as_float(c[12 + r] << 16), em[12 + r], __int_as_float(c[12 + r] & 0xffff0000));
    }
    s0 = mfma16(kf0, qf[h], s0);
    s1 = mfma16(kf1, qf[h], s1);
    s2 = mfma16(kf2, qf[h], s2);
    s3 = mfma16(kf3, qf[h], s3);

    float p00 = mk0.x ? 0.f : EXP2F(fminf(s0[0], SCLAMP));
    float p01 = mk0.y ? 0.f : EXP2F(fminf(s0[1], SCLAMP));
    float p02 = mk0.z ? 0.f : EXP2F(fminf(s0[2], SCLAMP));
    float p03 = mk0.w ? 0.f : EXP2F(fminf(s0[3], SCLAMP));
    float p10 = mk1.x ? 0.f : EXP2F(fminf(s1[0], SCLAMP));
    float p11 = mk1.y ? 0.f : EXP2F(fminf(s1[1], SCLAMP));
    float p12 = mk1.z ? 0.f : EXP2F(fminf(s1[2], SCLAMP));
    float p13 = mk1.w ? 0.f : EXP2F(fminf(s1[3], SCLAMP));
    float p20 = mk2.x ? 0.f : EXP2F(fminf(s2[0], SCLAMP));
    float p21 = mk2.y ? 0.f : EXP2F(fminf(s2[1], SCLAMP));
    float p22 = mk2.z ? 0.f : EXP2F(fminf(s2[2], SCLAMP));
    float p23 = mk2.w ? 0.f : EXP2F(fminf(s2[3], SCLAMP));
    float p30 = mk3.x ? 0.f : EXP2F(fminf(s3[0], SCLAMP));
    float p31 = mk3.y ? 0.f : EXP2F(fminf(s3[1], SCLAMP));
    float p32 = mk3.z ? 0.f : EXP2F(fminf(s3[2], SCLAMP));
    float p33 = mk3.w ? 0.f : EXP2F(fminf(s3[3], SCLAMP));

    psum[h] += (((p00 + p01) + (p02 + p03)) + ((p10 + p11) + (p12 + p13)))
             + (((p20 + p21) + (p22 + p23)) + ((p30 + p31) + (p32 + p33)));

    s16x4 pf0 = pack4(p00, p01, p02, p03);
    s16x4 pf1 = pack4(p10, p11, p12, p13);
    s16x4 pf2 = pack4(p20, p21, p22, p23);
    s16x4 pf3 = pack4(p30, p31, p32, p33);
    oacc[h] = mfma16(vf0, pf0, oacc[h]);
    oacc[h] = mfma16(vf1, pf1, oacc[h]);
    oacc[h] = mfma16(vf2, pf2, oacc[h]);
    oacc[h] = mfma16(vf3, pf3, oacc[h]);
  }

  // ---- epilogue (identical to verified r11/r13) ----
  #pragma unroll
  for (int h = 0; h < 8; ++h) {
    float s = psum[h];
    s += __shfl_xor(s, 16);
    s += __shfl_xor(s, 32);
    psum[h] = s;
  }
  if (lg == 0) {
    #pragma unroll
    for (int h = 0; h < 8; ++h) psL[(wid << 7) + (h << 4) + lq] = psum[h];
  }
  __syncthreads();   // all waves done with main loop (table now dead)

  #pragma unroll
  for (int h = 0; h < 8; ++h) {
    float tot = 0.f;
    #pragma unroll
    for (int w2 = 0; w2 < 8; ++w2) tot += psL[(w2 << 7) + (h << 4) + lq];
    float inv = (tot > 0.f) ? 1.f / tot : 0.f;
    obfL[((wid << 3) + h << 6) + lane] =
        pack4(oacc[h][0] * inv, oacc[h][1] * inv, oacc[h][2] * inv, oacc[h][3] * inv);
  }
  __syncthreads();

  {
    f32x4 d2a = (f32x4)0.f;
    #pragma unroll
    for (int s = 0; s < 8; ++s) {
      f32x4 fa = (f32x4)0.f;
      #pragma unroll
      for (int w2 = 0; w2 < 8; ++w2) {
        union { s16x4 v; int i[2]; } bb;
        bb.v = obfL[((w2 << 3) + s << 6) + lane];
        fa[0] += __int_as_float(bb.i[0] << 16);
        fa[1] += __int_as_float(bb.i[0] & 0xffff0000);
        fa[2] += __int_as_float(bb.i[1] << 16);
        fa[3] += __int_as_float(bb.i[1] & 0xffff0000);
      }
      s16x4 ob = pack4(fa[0], fa[1], fa[2], fa[3]);
      s16x4 wo = *(const s16x4*)&Wob[(((wid << 3) + s) << 8) + (lane << 2)];
      d2a = mfma16(wo, ob, d2a);
    }
    *(float4*)&out[((((b << 9) + qt + lq) << 7)) + (wid << 4) + (lg << 2)] =
        *(float4*)&d2a;
  }
}

extern "C" void kernel_launch(void* const* d_in, const int* in_sizes, int n_in,
                              void* d_out, int out_size, void* d_ws, size_t ws_size,
                              hipStream_t stream)
{
  const float* q    = (const float*)d_in[0];
  const unsigned char* mask = (const unsigned char*)d_in[1];
  const float* edge = (const float*)d_in[2];
  const float* Wq   = (const float*)d_in[3];
  const float* Wk   = (const float*)d_in[4];
  const float* Wv   = (const float*)d_in[5];
  const float* Wo   = (const float*)d_in[6];
  const float* mW1  = (const float*)d_in[7];
  const float* mb1  = (const float*)d_in[8];
  const float* mW2  = (const float*)d_in[9];
  const float* mb2  = (const float*)d_in[10];
  const float* mW3  = (const float*)d_in[11];
  const float* mb3  = (const float*)d_in[12];
  float* out = (float*)d_out;

  size_t per = (size_t)Hc * Bc * Nc * DKc;     // 2,097,152 bf16 elems per matrix
  short* Wt  = (short*)d_ws;                   // 49152
  short* Wob = Wt + 49152;                     // 16384
  short* Qb  = Wob + 16384;
  short* Kb  = Qb + per;
  short* Vt  = Kb + per;
  int* tabI  = (int*)(Vt + per);               // 8192 ints (32 KB), 16B-aligned
  int* flag  = tabI + 8192;                    // ~12.7 MB used

  prep_all<<<dim3(261), dim3(256), 0, stream>>>(Wq, Wk, Wv, Wo, mask, flag,
      mW1, mb1, mW2, mb2, mW3, mb3, Wt, Wob, tabI);
  qkv4<<<dim3(Bc * 32), dim3(256), 0, stream>>>(q, Wt, Qb, Kb, Vt);
  attn15<<<dim3(Bc * 32), dim3(512), 0, stream>>>(edge, mask, flag, Qb, Kb, Vt, Wob,
      tabI, out);
}

// Round 16
// 138.671 us; speedup vs baseline: 1.2381x; 1.2381x over previous
//
#include <hip/hip_runtime.h>
#include <hip/hip_bf16.h>
#include <float.h>

#define Bc 32
#define Nc 512
#define Dc 128
#define Hc 8
#define DKc 16
#define Ec 128
#define LOG2E 1.44269504088896340736f
#define SCLAMP 80.0f

typedef __attribute__((ext_vector_type(4))) short s16x4;
typedef __attribute__((ext_vector_type(8))) short s16x8;
typedef __attribute__((ext_vector_type(4))) float f32x4;

union BFU { __hip_bfloat16 b; short s; };
static __device__ inline short f2bf(float f) { BFU u; u.b = __float2bfloat16(f); return u.s; }
static __device__ inline s16x4 pack4(float a, float b, float c, float d) {
  s16x4 r; r[0] = f2bf(a); r[1] = f2bf(b); r[2] = f2bf(c); r[3] = f2bf(d); return r;
}

#if __has_builtin(__builtin_amdgcn_exp2f)
#define EXP2F(x) __builtin_amdgcn_exp2f(x)
#else
#define EXP2F(x) exp2f(x)
#endif

// D = A*B + C for 16x16x16 bf16. A[m=l&15][k=(l>>4)*4+i]; B[k=(l>>4)*4+i][n=l&15];
// C/D: col(n)=l&15, row(m)=(l>>4)*4+reg.
static __device__ inline f32x4 mfma16(s16x4 a, s16x4 b, f32x4 c) {
#if __has_builtin(__builtin_amdgcn_mfma_f32_16x16x16bf16_1k)
  return __builtin_amdgcn_mfma_f32_16x16x16bf16_1k(a, b, c, 0, 0, 0);
#else
  int lane = threadIdx.x & 63;
  int g = lane >> 4, base = lane & 15;
  int src0 = (base + 32 * g) & 63;
  int src1 = (base + 32 * g + 16) & 63;
  int ax = ((int*)&a)[0], ay = ((int*)&a)[1];
  int bx = ((int*)&b)[0], by = ((int*)&b)[1];
  int A0 = __shfl(ax, src0), A1 = __shfl(ay, src0);
  int A2 = __shfl(ax, src1), A3 = __shfl(ay, src1);
  int B0 = __shfl(bx, src0), B1 = __shfl(by, src0);
  int B2 = __shfl(bx, src1), B3 = __shfl(by, src1);
  if (g >= 2) { A0 = A1 = A2 = A3 = 0; B0 = B1 = B2 = B3 = 0; }
  s16x8 A8, B8;
  ((int*)&A8)[0] = A0; ((int*)&A8)[1] = A1; ((int*)&A8)[2] = A2; ((int*)&A8)[3] = A3;
  ((int*)&B8)[0] = B0; ((int*)&B8)[1] = B1; ((int*)&B8)[2] = B2; ((int*)&B8)[3] = B3;
  return __builtin_amdgcn_mfma_f32_16x16x32_bf16(A8, B8, c, 0, 0, 0);
#endif
}

// ---- prep: weight conv (0..255) + mask detector (256) + 1024-cell table (257..260) ----
// tabI[h*1024 + c] = (bf16(f(mid)*L)<<16) | bf16(a*L); cells over [-8,8), width 1/64.
__global__ __launch_bounds__(256) void prep_all(
    const float* __restrict__ Wq, const float* __restrict__ Wk, const float* __restrict__ Wv,
    const float* __restrict__ Wo,
    const unsigned char* __restrict__ m, int* __restrict__ flag,
    const float* __restrict__ mW1, const float* __restrict__ mb1,
    const float* __restrict__ mW2, const float* __restrict__ mb2,
    const float* __restrict__ mW3, const float* __restrict__ mb3,
    short* __restrict__ Wt, short* __restrict__ Wob, int* __restrict__ tabI)
{
  int blk = blockIdx.x;
  int t = threadIdx.x;

  if (blk == 256) {   // mask-format detector (single-writer)
    __shared__ int red[4];
    int any = 0;
    for (int u = t; u < 16384; u += 256)
      if ((u & 3) != 0 && m[u] != 0) any = 1;
    unsigned long long bal = __ballot(any != 0);
    if ((t & 63) == 0) red[t >> 6] = (bal != 0ULL) ? 1 : 0;
    __syncthreads();
    if (t == 0) *flag = red[0] | red[1] | red[2] | red[3];
    return;
  }

  if (blk >= 257) {   // cell table: exact MLP tangent-segment at cell midpoint
    __shared__ float wl[440];
    for (int u = t; u < 440; u += 256) {
      float v;
      if (u < 16) v = mW1[u];
      else if (u < 32)  v = mb1[u - 16];
      else if (u < 288) v = mW2[u - 32];
      else if (u < 304) v = mb2[u - 288];
      else if (u < 432) v = mW3[u - 304];
      else v = mb3[u - 432];
      wl[u] = v;
    }
    __syncthreads();
    int c = (blk - 257) * 256 + t;                       // 0..1023
    float mm = fmaf((float)c, 0.015625f, -7.9921875f);   // -8 + 1/128 + c/64

    float pre[16];
    #pragma unroll
    for (int u = 0; u < 16; ++u) pre[u] = fmaf(mm, wl[u], wl[16 + u]);
    float a2[16], v2[16];
    #pragma unroll
    for (int v = 0; v < 16; ++v) { a2[v] = 0.f; v2[v] = wl[288 + v]; }
    #pragma unroll
    for (int u = 0; u < 16; ++u) {
      bool act = pre[u] > 0.f;
      float w1 = act ? wl[u] : 0.f;
      float pp = act ? pre[u] : 0.f;
      #pragma unroll
      for (int v = 0; v < 16; ++v) {
        float w2 = wl[32 + u * 16 + v];
        a2[v] = fmaf(w1, w2, a2[v]);
        v2[v] = fmaf(pp, w2, v2[v]);
      }
    }
    float ah[8], fh[8];
    #pragma unroll
    for (int h = 0; h < 8; ++h) { ah[h] = 0.f; fh[h] = wl[432 + h]; }
    #pragma unroll
    for (int v = 0; v < 16; ++v) {
      bool act = v2[v] > 0.f;
      float av = act ? a2[v] : 0.f;
      float vv = act ? v2[v] : 0.f;
      #pragma unroll
      for (int h = 0; h < 8; ++h) {
        float w3 = wl[304 + v * 8 + h];
        ah[h] = fmaf(av, w3, ah[h]);
        fh[h] = fmaf(vv, w3, fh[h]);
      }
    }
    #pragma unroll
    for (int h = 0; h < 8; ++h) {
      int ab = (int)(unsigned short)(f2bf(ah[h] * LOG2E));
      int fb = ((int)f2bf(fh[h] * LOG2E)) << 16;
      tabI[h * 1024 + c] = fb | ab;                      // head-major for b32 LDS gather
    }
    return;
  }

  int o = blk * 256 + t;
  if (o < 49152) {
    int mat = o >> 14, r = o & 16383;
    int hk = r >> 7, d = r & 127;
    const float* src = (mat == 0) ? Wq : ((mat == 1) ? Wk : Wv);
    Wt[o] = f2bf(src[(hk >> 4) * 2048 + d * 16 + (hk & 15)]);
  } else {
    int o2 = o - 49152;
    int et = o2 >> 11, s = (o2 >> 8) & 7, lane = (o2 >> 2) & 63, i = o2 & 3;
    Wob[o2] = f2bf(Wo[(s * 16 + (lane >> 4) * 4 + i) * 128 + et * 16 + (lane & 15)]);
  }
}

// ---- kernel A: QKV projection via MFMA (unchanged, verified) ----
__global__ __launch_bounds__(256, 4) void qkv4(
    const float* __restrict__ q, const short* __restrict__ Wt,
    short* __restrict__ Qb, short* __restrict__ Kb, short* __restrict__ Vt)
{
  __shared__ short qs[16][136];
  int blk = blockIdx.x;
  int b = blk >> 5;
  int rt = (blk & 31) << 4;
  int t = threadIdx.x;
  int wid = t >> 6, lane = t & 63;
  int lq = lane & 15, lg = lane >> 4;

  #pragma unroll
  for (int it = 0; it < 2; ++it) {
    int u = t + it * 256;
    int row = u >> 5, c4 = (u & 31) << 2;
    float4 v = *(const float4*)&q[((((b << 9) + rt + row) << 7)) + c4];
    *(s16x4*)&qs[row][c4] = pack4(v.x, v.y, v.z, v.w);
  }
  __syncthreads();

  s16x4 af[8];
  #pragma unroll
  for (int ks = 0; ks < 8; ++ks)
    af[ks] = *(const s16x4*)&qs[lq][ks * 16 + lg * 4];

  #pragma unroll 1
  for (int pj = 0; pj < 3; ++pj) {
    const short* Wm = Wt + pj * 16384;
    #pragma unroll
    for (int c2 = 0; c2 < 2; ++c2) {
      int ct = wid * 2 + c2;
      f32x4 acc = (f32x4)0.f;
      #pragma unroll
      for (int ks = 0; ks < 8; ++ks) {
        s16x4 bf = *(const s16x4*)&Wm[(ct * 16 + lq) * 128 + ks * 16 + lg * 4];
        acc = mfma16(af[ks], bf, acc);
      }
      if (pj == 0) {
        s16x4 pk = pack4(acc[0] * (0.25f * LOG2E), acc[1] * (0.25f * LOG2E),
                         acc[2] * (0.25f * LOG2E), acc[3] * (0.25f * LOG2E));
        #pragma unroll
        for (int r = 0; r < 4; ++r)
          Qb[(ct << 18) + (b << 13) + ((rt + lg * 4 + r) << 4) + lq] = pk[r];
      } else if (pj == 1) {
        s16x4 pk = pack4(acc[0], acc[1], acc[2], acc[3]);
        #pragma unroll
        for (int r = 0; r < 4; ++r)
          Kb[(ct << 18) + (b << 13) + ((rt + lg * 4 + r) << 4) + lq] = pk[r];
      } else {
        s16x4 pk = pack4(acc[0], acc[1], acc[2], acc[3]);
        *(s16x4*)&Vt[(ct << 18) + (((b << 4) + lq) << 9) + rt + lg * 4] = pk;
      }
    }
  }
}

// decode one edge value -> LDS byte offset + in-cell delta (named scalars, no arrays)
#define DEC1(E, OFF, EM) { \
    float fx_ = fminf(fmaxf(fmaf((E), 64.f, 512.f), 0.f), 1023.f); \
    int ix_ = (int)fx_; \
    OFF = (unsigned)(ix_ << 2); \
    EM = (E) - fmaf((float)ix_, 0.015625f, -7.9921875f); }

// bias eval from table word C at delta EM
#define BIAS(C, EM) fmaf(__int_as_float((C) << 16), (EM), __int_as_float((C) & 0xffff0000))

// ---- kernel B: 8-wave attn, straight-line 4-way sub-chunk ILP (named scalars) ----
// 512 threads; wave w owns chunks {w, w+8, w+16, w+24}; 8x64B loads in flight up front.
// LDS 36864B: tabL int[8][1024] @0; epilogue overlay obfL [8w][8h][64] s16x4 @0
// + psL f32[8][8][16] @32768. Plain launch_bounds(512): natural VGPR, no forced tier
// (r15 lesson: pointer-array decode forced scratch; all state is named scalars here).
__global__ __launch_bounds__(512) void attn16(
    const float* __restrict__ edge, const unsigned char* __restrict__ maskB,
    const int* __restrict__ flag,
    const short* __restrict__ Qb, const short* __restrict__ Kb, const short* __restrict__ Vt,
    const short* __restrict__ Wob,
    const int* __restrict__ tabI,
    float* __restrict__ out)
{
  __shared__ __align__(16) char smem[36864];

  int t = threadIdx.x;
  int wid = t >> 6, lane = t & 63;
  int lq = lane & 15, lg = lane >> 4;
  int b = blockIdx.x >> 5;
  int qt = (blockIdx.x & 31) << 4;
  int mflag = *flag;

  s16x4* obfL = (s16x4*)smem;                 // [8w][8h][64] overlay
  float* psL = (float*)(smem + 32768);        // [8][8][16]

  const short* Kl = Kb + (b << 13) + (lq << 4) + (lg << 2);
  const short* Vl = Vt + (((b << 4) + lq) << 9) + (lg << 2);
  const short* Ql = Qb + (b << 13) + ((qt + lq) << 4) + (lg << 2);
  unsigned mbase = (((b << 9) + qt + lq) << 9) + (lg << 2);

  // issue all 4 sub-chunks' edge + mask loads up front (8 x 64B in flight)
  int jb0 = wid << 4, jb1 = (wid + 8) << 4, jb2 = (wid + 16) << 4, jb3 = (wid + 24) << 4;
  float4 ev0 = *(const float4*)&edge[mbase + jb0];
  float4 ev1 = *(const float4*)&edge[mbase + jb1];
  float4 ev2 = *(const float4*)&edge[mbase + jb2];
  float4 ev3 = *(const float4*)&edge[mbase + jb3];
  int mq0, mq1, mq2, mq3;   // 4-bit compressed masks
  if (mflag) {
    uchar4 u0 = *(const uchar4*)&maskB[mbase + jb0];
    uchar4 u1 = *(const uchar4*)&maskB[mbase + jb1];
    uchar4 u2 = *(const uchar4*)&maskB[mbase + jb2];
    uchar4 u3 = *(const uchar4*)&maskB[mbase + jb3];
    mq0 = (u0.x?1:0)|(u0.y?2:0)|(u0.z?4:0)|(u0.w?8:0);
    mq1 = (u1.x?1:0)|(u1.y?2:0)|(u1.z?4:0)|(u1.w?8:0);
    mq2 = (u2.x?1:0)|(u2.y?2:0)|(u2.z?4:0)|(u2.w?8:0);
    mq3 = (u3.x?1:0)|(u3.y?2:0)|(u3.z?4:0)|(u3.w?8:0);
  } else {
    const int* mi = (const int*)maskB;
    int4 m0 = *(const int4*)&mi[mbase + jb0];
    int4 m1 = *(const int4*)&mi[mbase + jb1];
    int4 m2 = *(const int4*)&mi[mbase + jb2];
    int4 m3 = *(const int4*)&mi[mbase + jb3];
    mq0 = (m0.x?1:0)|(m0.y?2:0)|(m0.z?4:0)|(m0.w?8:0);
    mq1 = (m1.x?1:0)|(m1.y?2:0)|(m1.z?4:0)|(m1.w?8:0);
    mq2 = (m2.x?1:0)|(m2.y?2:0)|(m2.z?4:0)|(m2.w?8:0);
    mq3 = (m3.x?1:0)|(m3.y?2:0)|(m3.z?4:0)|(m3.w?8:0);
  }

  // stage table (8192 ints = 2048 int4) — overlaps with outstanding edge/mask loads
  for (int u = t; u < 2048; u += 512)
    ((int4*)smem)[u] = ((const int4*)tabI)[u];

  s16x4 qf[8];
  #pragma unroll
  for (int h = 0; h < 8; ++h) qf[h] = *(const s16x4*)(Ql + (h << 18));

  f32x4 oacc[8];
  float psum[8];
  #pragma unroll
  for (int h = 0; h < 8; ++h) { oacc[h] = (f32x4)0.f; psum[h] = 0.f; }

  // decode: 16 named byte-offsets + 16 named deltas (no arrays, no pointers)
  unsigned o00, o01, o02, o03, o10, o11, o12, o13;
  unsigned o20, o21, o22, o23, o30, o31, o32, o33;
  float e00, e01, e02, e03, e10, e11, e12, e13;
  float e20, e21, e22, e23, e30, e31, e32, e33;
  DEC1(ev0.x, o00, e00) DEC1(ev0.y, o01, e01) DEC1(ev0.z, o02, e02) DEC1(ev0.w, o03, e03)
  DEC1(ev1.x, o10, e10) DEC1(ev1.y, o11, e11) DEC1(ev1.z, o12, e12) DEC1(ev1.w, o13, e13)
  DEC1(ev2.x, o20, e20) DEC1(ev2.y, o21, e21) DEC1(ev2.z, o22, e22) DEC1(ev2.w, o23, e23)
  DEC1(ev3.x, o30, e30) DEC1(ev3.y, o31, e31) DEC1(ev3.z, o32, e32) DEC1(ev3.w, o33, e33)

  __syncthreads();   // table staged

  // head loop: unroll 1 to bound transient pressure; ILP = 4 sub-chunk chains
  #pragma unroll 1
  for (int h = 0; h < 8; ++h) {
    const char* tb = smem + (h << 12);
    int c00 = *(const int*)(tb + o00), c01 = *(const int*)(tb + o01);
    int c02 = *(const int*)(tb + o02), c03 = *(const int*)(tb + o03);
    int c10 = *(const int*)(tb + o10), c11 = *(const int*)(tb + o11);
    int c12 = *(const int*)(tb + o12), c13 = *(const int*)(tb + o13);
    int c20 = *(const int*)(tb + o20), c21 = *(const int*)(tb + o21);
    int c22 = *(const int*)(tb + o22), c23 = *(const int*)(tb + o23);
    int c30 = *(const int*)(tb + o30), c31 = *(const int*)(tb + o31);
    int c32 = *(const int*)(tb + o32), c33 = *(const int*)(tb + o33);

    const short* Kh = Kl + (h << 18);
    const short* Vh = Vl + (h << 18);
    s16x4 kf0 = *(const s16x4*)(Kh + (jb0 << 4));
    s16x4 kf1 = *(const s16x4*)(Kh + (jb1 << 4));
    s16x4 kf2 = *(const s16x4*)(Kh + (jb2 << 4));
    s16x4 kf3 = *(const s16x4*)(Kh + (jb3 << 4));
    s16x4 vf0 = *(const s16x4*)(Vh + jb0);
    s16x4 vf1 = *(const s16x4*)(Vh + jb1);
    s16x4 vf2 = *(const s16x4*)(Vh + jb2);
    s16x4 vf3 = *(const s16x4*)(Vh + jb3);

    f32x4 s0, s1, s2, s3;
    s0[0] = BIAS(c00, e00); s0[1] = BIAS(c01, e01); s0[2] = BIAS(c02, e02); s0[3] = BIAS(c03, e03);
    s1[0] = BIAS(c10, e10); s1[1] = BIAS(c11, e11); s1[2] = BIAS(c12, e12); s1[3] = BIAS(c13, e13);
    s2[0] = BIAS(c20, e20); s2[1] = BIAS(c21, e21); s2[2] = BIAS(c22, e22); s2[3] = BIAS(c23, e23);
    s3[0] = BIAS(c30, e30); s3[1] = BIAS(c31, e31); s3[2] = BIAS(c32, e32); s3[3] = BIAS(c33, e33);

    s16x4 qh = qf[h];
    s0 = mfma16(kf0, qh, s0);
    s1 = mfma16(kf1, qh, s1);
    s2 = mfma16(kf2, qh, s2);
    s3 = mfma16(kf3, qh, s3);

    float p00 = (mq0 & 1) ? 0.f : EXP2F(fminf(s0[0], SCLAMP));
    float p01 = (mq0 & 2) ? 0.f : EXP2F(fminf(s0[1], SCLAMP));
    float p02 = (mq0 & 4) ? 0.f : EXP2F(fminf(s0[2], SCLAMP));
    float p03 = (mq0 & 8) ? 0.f : EXP2F(fminf(s0[3], SCLAMP));
    float p10 = (mq1 & 1) ? 0.f : EXP2F(fminf(s1[0], SCLAMP));
    float p11 = (mq1 & 2) ? 0.f : EXP2F(fminf(s1[1], SCLAMP));
    float p12 = (mq1 & 4) ? 0.f : EXP2F(fminf(s1[2], SCLAMP));
    float p13 = (mq1 & 8) ? 0.f : EXP2F(fminf(s1[3], SCLAMP));
    float p20 = (mq2 & 1) ? 0.f : EXP2F(fminf(s2[0], SCLAMP));
    float p21 = (mq2 & 2) ? 0.f : EXP2F(fminf(s2[1], SCLAMP));
    float p22 = (mq2 & 4) ? 0.f : EXP2F(fminf(s2[2], SCLAMP));
    float p23 = (mq2 & 8) ? 0.f : EXP2F(fminf(s2[3], SCLAMP));
    float p30 = (mq3 & 1) ? 0.f : EXP2F(fminf(s3[0], SCLAMP));
    float p31 = (mq3 & 2) ? 0.f : EXP2F(fminf(s3[1], SCLAMP));
    float p32 = (mq3 & 4) ? 0.f : EXP2F(fminf(s3[2], SCLAMP));
    float p33 = (mq3 & 8) ? 0.f : EXP2F(fminf(s3[3], SCLAMP));

    psum[h] += (((p00 + p01) + (p02 + p03)) + ((p10 + p11) + (p12 + p13)))
             + (((p20 + p21) + (p22 + p23)) + ((p30 + p31) + (p32 + p33)));

    s16x4 pf0 = pack4(p00, p01, p02, p03);
    s16x4 pf1 = pack4(p10, p11, p12, p13);
    s16x4 pf2 = pack4(p20, p21, p22, p23);
    s16x4 pf3 = pack4(p30, p31, p32, p33);
    f32x4 oa = oacc[h];
    oa = mfma16(vf0, pf0, oa);
    oa = mfma16(vf1, pf1, oa);
    oa = mfma16(vf2, pf2, oa);
    oa = mfma16(vf3, pf3, oa);
    oacc[h] = oa;
  }

  // ---- epilogue (identical to verified r11/r13) ----
  #pragma unroll
  for (int h = 0; h < 8; ++h) {
    float s = psum[h];
    s += __shfl_xor(s, 16);
    s += __shfl_xor(s, 32);
    psum[h] = s;
  }
  if (lg == 0) {
    #pragma unroll
    for (int h = 0; h < 8; ++h) psL[(wid << 7) + (h << 4) + lq] = psum[h];
  }
  __syncthreads();   // all waves done with main loop (table now dead)

  #pragma unroll
  for (int h = 0; h < 8; ++h) {
    float tot = 0.f;
    #pragma unroll
    for (int w2 = 0; w2 < 8; ++w2) tot += psL[(w2 << 7) + (h << 4) + lq];
    float inv = (tot > 0.f) ? 1.f / tot : 0.f;
    obfL[((wid << 3) + h << 6) + lane] =
        pack4(oacc[h][0] * inv, oacc[h][1] * inv, oacc[h][2] * inv, oacc[h][3] * inv);
  }
  __syncthreads();

  {
    f32x4 d2a = (f32x4)0.f;
    #pragma unroll
    for (int s = 0; s < 8; ++s) {
      f32x4 fa = (f32x4)0.f;
      #pragma unroll
      for (int w2 = 0; w2 < 8; ++w2) {
        union { s16x4 v; int i[2]; } bb;
        bb.v = obfL[((w2 << 3) + s << 6) + lane];
        fa[0] += __int_as_float(bb.i[0] << 16);
        fa[1] += __int_as_float(bb.i[0] & 0xffff0000);
        fa[2] += __int_as_float(bb.i[1] << 16);
        fa[3] += __int_as_float(bb.i[1] & 0xffff0000);
      }
      s16x4 ob = pack4(fa[0], fa[1], fa[2], fa[3]);
      s16x4 wo = *(const s16x4*)&Wob[(((wid << 3) + s) << 8) + (lane << 2)];
      d2a = mfma16(wo, ob, d2a);
    }
    *(float4*)&out[((((b << 9) + qt + lq) << 7)) + (wid << 4) + (lg << 2)] =
        *(float4*)&d2a;
  }
}

extern "C" void kernel_launch(void* const* d_in, const int* in_sizes, int n_in,
                              void* d_out, int out_size, void* d_ws, size_t ws_size,
                              hipStream_t stream)
{
  const float* q    = (const float*)d_in[0];
  const unsigned char* mask = (const unsigned char*)d_in[1];
  const float* edge = (const float*)d_in[2];
  const float* Wq   = (const float*)d_in[3];
  const float* Wk   = (const float*)d_in[4];
  const float* Wv   = (const float*)d_in[5];
  const float* Wo   = (const float*)d_in[6];
  const float* mW1  = (const float*)d_in[7];
  const float* mb1  = (const float*)d_in[8];
  const float* mW2  = (const float*)d_in[9];
  const float* mb2  = (const float*)d_in[10];
  const float* mW3  = (const float*)d_in[11];
  const float* mb3  = (const float*)d_in[12];
  float* out = (float*)d_out;

  size_t per = (size_t)Hc * Bc * Nc * DKc;     // 2,097,152 bf16 elems per matrix
  short* Wt  = (short*)d_ws;                   // 49152
  short* Wob = Wt + 49152;                     // 16384
  short* Qb  = Wob + 16384;
  short* Kb  = Qb + per;
  short* Vt  = Kb + per;
  int* tabI  = (int*)(Vt + per);               // 8192 ints (32 KB), 16B-aligned
  int* flag  = tabI + 8192;                    // ~12.7 MB used

  prep_all<<<dim3(261), dim3(256), 0, stream>>>(Wq, Wk, Wv, Wo, mask, flag,
      mW1, mb1, mW2, mb2, mW3, mb3, Wt, Wob, tabI);
  qkv4<<<dim3(Bc * 32), dim3(256), 0, stream>>>(q, Wt, Qb, Kb, Vt);
  attn16<<<dim3(Bc * 32), dim3(512), 0, stream>>>(edge, mask, flag, Qb, Kb, Vt, Wob,
      tabI, out);
}